// Round 1
// 238.432 us; speedup vs baseline: 1.2011x; 1.2011x over previous
//
#include <hip/hip_runtime.h>

// Problem constants
#define BB 16
#define NL 256
#define RR 24
#define LL 32
#define NN (NL*NL)        // 65536
#define BNN (BB*NN)       // 1048576
#define TT 64             // FW tile

// Output layout (float32), reference return order.
#define O_TDT 0
#define O_RT  16
#define O_TAT 32
#define O_TD  96
#define O_UNS 112
#define O_TTR 128
#define O_TT  144
#define O_ND  1048720

// Packed (dist, hops) in one f64: v = dist + hops * 2^-30.
// dists are exact multiples of 2^-17 (f32 legs >= 90 -> ulp >= 2^-17; cumsum
// diffs preserve it), hops << 2^13, dist < 2^23 -> packing exact in 53-bit
// mantissa; f64 add distributes over both fields; f64 min = lexicographic
// (dist, then hops). Relaxation = v_add_f64 + v_min_f64 (2 insts vs 5).
#define HSC 9.3132257461547852e-10   // 2^-30
#define H2  1073741824.0             // 2^30
#define HMASK 8191

// LDS: rows of 64 doubles, 16B (double2) chunks XOR-swizzled by row.
#define RIDX(r, c2) (((r)<<6) + ((((c2) ^ ((r)&31)))<<1))
#define LDD(A, r, c2) (*(double2*)&A[RIDX((r),(c2))])

// ---------------- init: dist = INF packed, diag = 0, accumulators = 0 --------
__global__ __launch_bounds__(1024) void k_init(double2* __restrict__ dist2, float* __restrict__ acc){
    int idx = blockIdx.x*1024 + threadIdx.x;      // one double2 per thread
    double inf = __builtin_huge_val();
    double2 v = make_double2(inf, inf);
    int q = (idx*2) & (NN-1);                     // within-batch flat index
    int r = q % 257;                              // diag at q % (NL+1) == 0
    if (r == 0)   v.x = 0.0;
    if (r == 256) v.y = 0.0;                      // (q+1) % 257 == 0
    dist2[idx] = v;
    if (blockIdx.x == 0 && threadIdx.x < 256) acc[threadIdx.x] = 0.f;
}

// ---------------- route edges: one wave per (b,r), packed atomicMin ----------
__global__ void k_routes(const float* __restrict__ dtm, const int* __restrict__ routes,
                         unsigned long long* __restrict__ dist, float* __restrict__ acc){
    int br = blockIdx.x; int b = br / RR, r = br % RR;
    int lane = threadIdx.x;
    __shared__ int   s[LL];
    __shared__ float lf[LL], lr[LL], cf[LL], cr[LL];
    if (lane < LL) s[lane] = routes[(b*RR + r)*LL + lane];
    __syncthreads();
    if (lane < LL-1){
        int a0 = s[lane], a1 = s[lane+1];
        const float* dt = dtm + b*NN;
        lf[lane] = dt[a0*NL + a1] + 60.0f;   // MEAN_STOP_TIME_S
        lr[lane] = dt[a1*NL + a0] + 60.0f;
    }
    __syncthreads();
    if (lane == 0){
        float af = 0.f, ar = 0.f;
        cf[0] = 0.f; cr[0] = 0.f;
        for (int l = 0; l < LL-1; l++){
            af += lf[l]; ar += lr[l];
            cf[l+1] = af; cr[l+1] = ar;
        }
        atomicAdd(&acc[b*16 + 1], af + ar);  // total_route_time
    }
    __syncthreads();
    for (int p = lane; p < LL*LL; p += 64){
        int i = p >> 5, j = p & 31;
        if (j > i){
            double vf = (double)(cf[j] - cf[i]) + HSC;   // hops = 1
            double vr = (double)(cr[j] - cr[i]) + HSC;
            atomicMin(&dist[b*NN + s[i]*NL + s[j]], (unsigned long long)__double_as_longlong(vf));
            atomicMin(&dist[b*NN + s[j]*NL + s[i]], (unsigned long long)__double_as_longlong(vr));
        }
    }
}

// ---------------- one full FW round in a single dispatch -----------------------
// dst(ti,tj) = min(D0, C0 (x) K* (x) B0) on packed f64; 256 blocks x 512 thr.
__global__ __launch_bounds__(512) void k_fw_round(
        const double* __restrict__ src, double* __restrict__ dst, int kb){
    int b  = blockIdx.y;
    int m  = blockIdx.x;
    int ti = m >> 2, tj = m & 3;
    int t  = threadIdx.x;
    int rp  = (t >> 4) * 2;        // 2 owned rows: rp, rp+1
    int cch = t & 15;              // owned col chunk (4 doubles)
    int c04 = cch * 4;
    __shared__ double KD[4096];    // K -> K*; later C0
    __shared__ double BD[4096];    // B0; later M = K* (x) B0
    const double* Kg = src + b*NN + kb*TT*(NL+1);
    const double* Bg = src + b*NN + kb*TT*NL + tj*TT;
    const double* Cg = src + b*NN + ti*TT*NL + kb*TT;
    const double* Dg = src + b*NN + ti*TT*NL + tj*TT;

    // ---- early prefetch C0 and D0 into registers (hidden under closure) ----
    double c0[2][4], d0[2][4];
    #pragma unroll
    for (int i = 0; i < 2; i++){
        double2 ca = *(const double2*)(Cg + (rp+i)*NL + c04);
        double2 cb = *(const double2*)(Cg + (rp+i)*NL + c04 + 2);
        c0[i][0]=ca.x; c0[i][1]=ca.y; c0[i][2]=cb.x; c0[i][3]=cb.y;
        double2 da = *(const double2*)(Dg + (rp+i)*NL + c04);
        double2 db = *(const double2*)(Dg + (rp+i)*NL + c04 + 2);
        d0[i][0]=da.x; d0[i][1]=da.y; d0[i][2]=db.x; d0[i][3]=db.y;
    }

    // ---- stage K and B0 into LDS (2 rows' worth per thread per matrix) ----
    #pragma unroll
    for (int u = 0; u < 2; u++){
        int fid = u*512 + t;             // 0..1023
        int row = fid >> 4, cc = fid & 15;
        const double* kp = Kg + row*NL + cc*4;
        double2 k0 = *(const double2*)kp, k1 = *(const double2*)(kp+2);
        const double* bp = Bg + row*NL + cc*4;
        double2 b0 = *(const double2*)bp, b1 = *(const double2*)(bp+2);
        LDD(KD,row,cc*2)   = k0; LDD(KD,row,cc*2+1) = k1;
        LDD(BD,row,cc*2)   = b0; LDD(BD,row,cc*2+1) = b1;
    }
    __syncthreads();

    // ---- in-LDS hierarchical closure of K (sub-tile 16, 4 sub-rounds) ----
    for (int skb = 0; skb < 4; skb++){
        int s0 = skb*16, sc2 = skb*8;
        // p1': wave 0 closes 16x16 diag sub-tile via shfl (no barriers)
        if (t < 64){
            int i = t >> 2, jg = t & 3, rr = s0 + i, cb = sc2 + jg*2;
            double2 m0 = LDD(KD, rr, cb), m1 = LDD(KD, rr, cb+1);
            double md[4] = {m0.x, m0.y, m1.x, m1.y};
            #pragma unroll
            for (int k = 0; k < 16; k++){
                double rd[4];
                #pragma unroll
                for (int c = 0; c < 4; c++) rd[c] = __shfl(md[c], (k<<2)|jg);
                double cd = __shfl(md[k&3], (i<<2)|(k>>2));
                #pragma unroll
                for (int c = 0; c < 4; c++) md[c] = fmin(md[c], cd + rd[c]);
            }
            LDD(KD, rr, cb)   = make_double2(md[0], md[1]);
            LDD(KD, rr, cb+1) = make_double2(md[2], md[3]);
        }
        __syncthreads();
        // p2': 0..255 row strip (16 band rows x 64 cols), 256..511 col strip
        // (64 rows x 16 band cols). Band-square double-write is a benign
        // same-value race. Uniform barriers.
        double sd[4];
        int wrow, wc2;
        if (t < 256){
            int rsr = s0 + (t >> 4);
            wrow = rsr; wc2 = (t & 15)*2;
            double2 v0 = LDD(KD, rsr, wc2), v1 = LDD(KD, rsr, wc2+1);
            sd[0]=v0.x; sd[1]=v0.y; sd[2]=v1.x; sd[3]=v1.y;
            #pragma unroll
            for (int k = 0; k < 16; k++){
                double ad = KD[RIDX(rsr, sc2+(k>>1)) + (k&1)];
                double2 b0 = LDD(KD, s0+k, wc2), b1 = LDD(KD, s0+k, wc2+1);
                sd[0] = fmin(sd[0], ad + b0.x);
                sd[1] = fmin(sd[1], ad + b0.y);
                sd[2] = fmin(sd[2], ad + b1.x);
                sd[3] = fmin(sd[3], ad + b1.y);
            }
        } else {
            int t2 = t - 256;
            int csr = t2 >> 2;
            wrow = csr; wc2 = sc2 + (t2 & 3)*2;
            double2 v0 = LDD(KD, csr, wc2), v1 = LDD(KD, csr, wc2+1);
            sd[0]=v0.x; sd[1]=v0.y; sd[2]=v1.x; sd[3]=v1.y;
            #pragma unroll
            for (int k = 0; k < 16; k++){
                double ad = KD[RIDX(csr, sc2+(k>>1)) + (k&1)];
                double2 b0 = LDD(KD, s0+k, wc2), b1 = LDD(KD, s0+k, wc2+1);
                sd[0] = fmin(sd[0], ad + b0.x);
                sd[1] = fmin(sd[1], ad + b0.y);
                sd[2] = fmin(sd[2], ad + b1.x);
                sd[3] = fmin(sd[3], ad + b1.y);
            }
        }
        __syncthreads();   // all p2' reads done
        LDD(KD, wrow, wc2)   = make_double2(sd[0], sd[1]);
        LDD(KD, wrow, wc2+1) = make_double2(sd[2], sd[3]);
        __syncthreads();
        // p3': full 64x64, 2x4 per thread, k-blocked x4, barrier-free k loop
        double dd[2][4];
        #pragma unroll
        for (int i = 0; i < 2; i++){
            double2 v0 = LDD(KD, rp+i, cch*2), v1 = LDD(KD, rp+i, cch*2+1);
            dd[i][0]=v0.x; dd[i][1]=v0.y; dd[i][2]=v1.x; dd[i][3]=v1.y;
        }
        #pragma unroll
        for (int q4 = 0; q4 < 4; q4++){
            double a[2][4], bm[4][4];
            #pragma unroll
            for (int i = 0; i < 2; i++){
                double2 a0 = LDD(KD, rp+i, sc2+q4*2), a1 = LDD(KD, rp+i, sc2+q4*2+1);
                a[i][0]=a0.x; a[i][1]=a0.y; a[i][2]=a1.x; a[i][3]=a1.y;
            }
            int kr = s0 + q4*4;
            #pragma unroll
            for (int q = 0; q < 4; q++){
                double2 b0 = LDD(KD, kr+q, cch*2), b1 = LDD(KD, kr+q, cch*2+1);
                bm[q][0]=b0.x; bm[q][1]=b0.y; bm[q][2]=b1.x; bm[q][3]=b1.y;
            }
            #pragma unroll
            for (int q = 0; q < 4; q++)
            #pragma unroll
            for (int i = 0; i < 2; i++)
            #pragma unroll
            for (int j = 0; j < 4; j++)
                dd[i][j] = fmin(dd[i][j], a[i][q] + bm[q][j]);
        }
        __syncthreads();   // all p3' reads done
        #pragma unroll
        for (int i = 0; i < 2; i++){
            LDD(KD, rp+i, cch*2)   = make_double2(dd[i][0], dd[i][1]);
            LDD(KD, rp+i, cch*2+1) = make_double2(dd[i][2], dd[i][3]);
        }
        __syncthreads();
    }

    // ---- M = K* (x) B0 (K* 0-diag -> includes identity), 2x4, k-blocked ----
    double inf = __builtin_huge_val();
    double md[2][4];
    #pragma unroll
    for (int i = 0; i < 2; i++)
    #pragma unroll
    for (int j = 0; j < 4; j++) md[i][j] = inf;
    #pragma unroll 4
    for (int q4 = 0; q4 < 16; q4++){
        double a[2][4], bm[4][4];
        #pragma unroll
        for (int i = 0; i < 2; i++){
            double2 a0 = LDD(KD, rp+i, q4*2), a1 = LDD(KD, rp+i, q4*2+1);
            a[i][0]=a0.x; a[i][1]=a0.y; a[i][2]=a1.x; a[i][3]=a1.y;
        }
        int kr = q4*4;
        #pragma unroll
        for (int q = 0; q < 4; q++){
            double2 b0 = LDD(BD, kr+q, cch*2), b1 = LDD(BD, kr+q, cch*2+1);
            bm[q][0]=b0.x; bm[q][1]=b0.y; bm[q][2]=b1.x; bm[q][3]=b1.y;
        }
        #pragma unroll
        for (int q = 0; q < 4; q++)
        #pragma unroll
        for (int i = 0; i < 2; i++)
        #pragma unroll
        for (int j = 0; j < 4; j++)
            md[i][j] = fmin(md[i][j], a[i][q] + bm[q][j]);
    }
    __syncthreads();   // all K*/B0 reads done
    // write M over B0; write prefetched C0 over K*
    #pragma unroll
    for (int i = 0; i < 2; i++){
        LDD(BD, rp+i, cch*2)   = make_double2(md[i][0], md[i][1]);
        LDD(BD, rp+i, cch*2+1) = make_double2(md[i][2], md[i][3]);
        LDD(KD, rp+i, cch*2)   = make_double2(c0[i][0], c0[i][1]);
        LDD(KD, rp+i, cch*2+1) = make_double2(c0[i][2], c0[i][3]);
    }
    __syncthreads();

    // ---- dst = min(D0, C0 (x) M) ----
    double dd[2][4];
    #pragma unroll
    for (int i = 0; i < 2; i++)
    #pragma unroll
    for (int j = 0; j < 4; j++) dd[i][j] = d0[i][j];
    #pragma unroll 4
    for (int q4 = 0; q4 < 16; q4++){
        double a[2][4], bm[4][4];
        #pragma unroll
        for (int i = 0; i < 2; i++){
            double2 a0 = LDD(KD, rp+i, q4*2), a1 = LDD(KD, rp+i, q4*2+1);
            a[i][0]=a0.x; a[i][1]=a0.y; a[i][2]=a1.x; a[i][3]=a1.y;
        }
        int kr = q4*4;
        #pragma unroll
        for (int q = 0; q < 4; q++){
            double2 b0 = LDD(BD, kr+q, cch*2), b1 = LDD(BD, kr+q, cch*2+1);
            bm[q][0]=b0.x; bm[q][1]=b0.y; bm[q][2]=b1.x; bm[q][3]=b1.y;
        }
        #pragma unroll
        for (int q = 0; q < 4; q++)
        #pragma unroll
        for (int i = 0; i < 2; i++)
        #pragma unroll
        for (int j = 0; j < 4; j++)
            dd[i][j] = fmin(dd[i][j], a[i][q] + bm[q][j]);
    }
    double* Od = dst + b*NN + ti*TT*NL + tj*TT;
    #pragma unroll
    for (int i = 0; i < 2; i++){
        *(double2*)(Od + (rp+i)*NL + c04)     = make_double2(dd[i][0], dd[i][1]);
        *(double2*)(Od + (rp+i)*NL + c04 + 2) = make_double2(dd[i][2], dd[i][3]);
    }
}

// ---------------- epilogue: trip_times + reductions + fused finalize ----------
__global__ __launch_bounds__(1024) void k_epi(const double2* __restrict__ dist2,
        const float4* __restrict__ demand4, float* __restrict__ out, float* __restrict__ acc){
    int b = blockIdx.y;
    int fid = (b*NN >> 2) + blockIdx.x*1024 + threadIdx.x;   // float4/demand index
    long long q2 = (long long)fid * 2;
    double2 va = dist2[q2], vb = dist2[q2+1];
    double vs[4] = {va.x, va.y, vb.x, vb.y};
    float4 mv = demand4[fid];
    float ms[4] = {mv.x, mv.y, mv.z, mv.w};
    float s0=0,s1=0,s2=0,s3=0,s4=0,s5=0,s6=0,s7=0,s8=0;
    float tts[4];
    #pragma unroll
    for (int e = 0; e < 4; e++){
        double v = vs[e];
        bool np = !(v < 1e37);
        double vv = np ? 0.0 : v;
        int h = (int)(((long long)(vv * H2)) & (long long)HMASK);
        float d = (float)vv;
        float dm = ms[e];
        float pl = np ? 0.f : (float)(h + 1);
        float tr = (pl == 0.f) ? 0.f : pl - 2.f;
        float tt = np ? 0.f : d + tr*300.f;   // AVG_TRANSFER_WAIT_TIME_S
        tts[e] = tt;
        s0 += dm*tt;
        s1 += dm*tr;
        s2 += np ? dm : 0.f;
        s3 += dm;
        s4 += (np && dm > 0.f) ? 1.f : 0.f;
        s5 += (tr == 0.f) ? dm : 0.f;
        s6 += (tr == 1.f) ? dm : 0.f;
        s7 += (tr == 2.f) ? dm : 0.f;
        s8 += (tr > 2.f) ? dm : 0.f;
    }
    ((float4*)(out + O_TT))[fid] = make_float4(tts[0],tts[1],tts[2],tts[3]);
    #define RED(x) { x += __shfl_down(x,32); x += __shfl_down(x,16); x += __shfl_down(x,8); \
                     x += __shfl_down(x,4);  x += __shfl_down(x,2);  x += __shfl_down(x,1); }
    RED(s0) RED(s1) RED(s2) RED(s3) RED(s4) RED(s5) RED(s6) RED(s7) RED(s8)
    __shared__ float red[16][9];
    int w = threadIdx.x >> 6;
    if ((threadIdx.x & 63) == 0){
        red[w][0]=s0; red[w][1]=s1; red[w][2]=s2; red[w][3]=s3; red[w][4]=s4;
        red[w][5]=s5; red[w][6]=s6; red[w][7]=s7; red[w][8]=s8;
    }
    __syncthreads();
    if (threadIdx.x < 9){
        float v = 0.f;
        #pragma unroll
        for (int ww = 0; ww < 16; ww++) v += red[ww][threadIdx.x];
        // acc slots: 0 tdt, 1 rt, 2 ttrans, 3 uns, 4 tdem, 5 ndis, 6 b0, 7 b1, 8 b2, 9 bun
        int slot = (threadIdx.x == 0) ? 0 : threadIdx.x + 1;
        atomicAdd(&acc[b*16 + slot], v);
    }
    __syncthreads();
    __shared__ int isLast;
    if (threadIdx.x == 0){
        unsigned prev = atomicAdd((unsigned int*)(acc + 255), 1u);
        isLast = (prev == 255u) ? 1 : 0;   // 16x16 = 256 blocks
    }
    __syncthreads();
    if (isLast && threadIdx.x < BB){
        int bb = threadIdx.x;
        float a[10];
        #pragma unroll
        for (int s = 0; s < 10; s++) a[s] = atomicAdd(&acc[bb*16 + s], 0.f);  // coherent read
        out[O_TDT + bb] = a[0];
        out[O_RT  + bb] = a[1];
        out[O_TAT + 4*bb + 0] = a[6];
        out[O_TAT + 4*bb + 1] = a[7];
        out[O_TAT + 4*bb + 2] = a[8];
        out[O_TAT + 4*bb + 3] = a[9] + a[3];
        out[O_TD  + bb] = a[4];
        out[O_UNS + bb] = a[3];
        out[O_TTR + bb] = a[2];
        out[O_ND  + bb] = a[5];
    }
}

extern "C" void kernel_launch(void* const* d_in, const int* in_sizes, int n_in,
                              void* d_out, int out_size, void* d_ws, size_t ws_size,
                              hipStream_t stream){
    (void)in_sizes; (void)n_in; (void)out_size; (void)ws_size;
    const float* dtm    = (const float*)d_in[0];
    const float* demand = (const float*)d_in[1];
    const int*   routes = (const int*)d_in[2];
    float* out   = (float*)d_out;
    double* distA = (double*)d_ws;          // buf0 packed (dist,hops)
    double* distB = distA + BNN;            // buf1 packed
    float*  acc   = (float*)(distB + BNN);  // 256 floats (incl. counter at [255])

    k_init  <<<512, 1024, 0, stream>>>((double2*)distA, acc);
    k_routes<<<BB*RR,  64, 0, stream>>>(dtm, routes, (unsigned long long*)distA, acc);
    // 4 rounds, double-buffered: 0: A->B, 1: B->A, 2: A->B, 3: B->A (ends in A)
    k_fw_round<<<dim3(16,BB), 512, 0, stream>>>(distA, distB, 0);
    k_fw_round<<<dim3(16,BB), 512, 0, stream>>>(distB, distA, 1);
    k_fw_round<<<dim3(16,BB), 512, 0, stream>>>(distA, distB, 2);
    k_fw_round<<<dim3(16,BB), 512, 0, stream>>>(distB, distA, 3);
    k_epi<<<dim3(16,BB), 1024, 0, stream>>>((const double2*)distA,
                                            (const float4*)demand, out, acc);
}